// Round 1
// baseline (229.573 us; speedup 1.0000x reference)
//
#include <hip/hip_runtime.h>

// Problem constants (from reference):
//   x: [B=64, C=12, 224, 224] f32; w: [C=12, E=768] f32
//   pooled[b,c,i,j] = sum of 16x16 patch; out[b, i*14+j, e] = sum_c pooled * w[c,e]
// Memory-bound: 154 MB read + 38.5 MB write -> ~31 us roofline @6.3 TB/s.

#define BATCH 64
#define CH    12
#define IMGD  224
#define NP    14          // patches per side
#define NPP   (NP * NP)   // 196 patches per image
#define EMB   768

__global__ __launch_bounds__(192) void dcsp_fused_kernel(
    const float* __restrict__ x,
    const float* __restrict__ w,
    float* __restrict__ out)
{
    const int blk = blockIdx.x;          // b*196 + p
    const int b = blk / NPP;
    const int p = blk - b * NPP;
    const int i = p / NP;
    const int j = p - i * NP;

    const int t    = threadIdx.x;        // 0..191
    const int lane = t & 63;
    const int wave = t >> 6;             // 0..2

    __shared__ float pooled[CH];

    // lane -> position inside the 16x16 patch: row = lane>>2, 4-float quad = lane&3
    const int r = lane >> 2;
    const int q = lane & 3;
    const int row = i * 16 + r;
    const int col = j * 16 + q * 4;

    // Each wave covers channels {wave, wave+3, wave+6, wave+9}
    float s[4];
#pragma unroll
    for (int k = 0; k < 4; ++k) {
        const int c = wave + 3 * k;
        const float4 v = *reinterpret_cast<const float4*>(
            x + (((size_t)(b * CH + c) * IMGD + row) * IMGD + col));
        s[k] = (v.x + v.y) + (v.z + v.w);
    }

    // full-wave (64-lane) shuffle reduction of the 4 partials
#pragma unroll
    for (int off = 32; off > 0; off >>= 1) {
#pragma unroll
        for (int k = 0; k < 4; ++k)
            s[k] += __shfl_down(s[k], off, 64);
    }
    if (lane == 0) {
#pragma unroll
        for (int k = 0; k < 4; ++k)
            pooled[wave + 3 * k] = s[k];
    }
    __syncthreads();

    // Step 2: each thread writes one float4 of the 768-wide embedding row.
    // pooled[c] is an LDS broadcast (conflict-free); w is 36 KB -> L2-resident.
    float4 acc = make_float4(0.f, 0.f, 0.f, 0.f);
    const float4* __restrict__ w4 = reinterpret_cast<const float4*>(w);
#pragma unroll
    for (int c = 0; c < CH; ++c) {
        const float  pc = pooled[c];
        const float4 wv = w4[c * (EMB / 4) + t];
        acc.x += pc * wv.x;
        acc.y += pc * wv.y;
        acc.z += pc * wv.z;
        acc.w += pc * wv.w;
    }
    reinterpret_cast<float4*>(out)[(size_t)blk * (EMB / 4) + t] = acc;
}

extern "C" void kernel_launch(void* const* d_in, const int* in_sizes, int n_in,
                              void* d_out, int out_size, void* d_ws, size_t ws_size,
                              hipStream_t stream) {
    const float* x = (const float*)d_in[0];
    const float* w = (const float*)d_in[1];
    float* out = (float*)d_out;

    dcsp_fused_kernel<<<BATCH * NPP, 192, 0, stream>>>(x, w, out);
}

// Round 2
// 226.856 us; speedup vs baseline: 1.0120x; 1.0120x over previous
//
#include <hip/hip_runtime.h>

// x: [B=64, C=12, 224, 224] f32; w: [C=12, E=768] f32
// pooled[b,c,i,j] = sum of 16x16 patch; out[b, i*14+j, e] = sum_c pooled * w[c,e]
// Memory-bound: 154 MB read + 38.5 MB write.
// R1: block = one PAIR of horizontally adjacent patches so every global load
// covers a full, aligned 128 B cache line (row*896 + jj*128). R0's 64 B
// half-line segments were refetched by the neighboring block on another XCD
// (per-XCD L2 not shared) -> ~2x x-fetch.

#define BATCH 64
#define CH    12
#define IMGD  224
#define NP    14          // patches per side
#define NPP   (NP * NP)   // 196 patches per image
#define EMB   768
#define E4    (EMB / 4)   // 192 float4 per output row

__global__ __launch_bounds__(384) void dcsp_fused_kernel(
    const float* __restrict__ x,
    const float* __restrict__ w,
    float* __restrict__ out)
{
    // grid: b * (14*7) + i*7 + jj   (jj = patch-pair index, covers j=2jj, 2jj+1)
    const int blk = blockIdx.x;
    const int b  = blk / (NP * (NP / 2));
    const int r0 = blk - b * (NP * (NP / 2));
    const int i  = r0 / (NP / 2);
    const int jj = r0 - i * (NP / 2);

    const int t    = threadIdx.x;        // 0..383
    const int lane = t & 63;
    const int wave = t >> 6;             // 0..5

    __shared__ float pooled[2][CH];      // [left/right patch][channel]

    // lane -> (row-octet, col-quad) inside the 16x32 region:
    //   r8 = lane>>3 (0..7 rows), q = lane&7 (0..7 float4-quads = 128 B line)
    const int r8 = lane >> 3;
    const int q  = lane & 7;
    const int colbase = jj * 32 + q * 4;

    // wave w handles channels 2w and 2w+1; two half-region loads each (16 rows)
    float s[2] = {0.f, 0.f};
#pragma unroll
    for (int k = 0; k < 2; ++k) {
        const int c = wave * 2 + k;
        const size_t chbase = (size_t)(b * CH + c) * IMGD * IMGD;
#pragma unroll
        for (int half = 0; half < 2; ++half) {
            const int row = i * 16 + half * 8 + r8;
            const float4 v = *reinterpret_cast<const float4*>(
                x + chbase + (size_t)row * IMGD + colbase);
            s[k] += (v.x + v.y) + (v.z + v.w);
        }
    }

    // xor-shuffle reduce over masks {1,2,8,16,32}: sums the 32 lanes sharing
    // bit 2 (q<4 = left patch, q>=4 = right patch)
#pragma unroll
    for (int m = 0; m < 5; ++m) {
        const int mask = (1 << m) < 4 ? (1 << m) : (1 << (m + 1)); // 1,2,8,16,32
#pragma unroll
        for (int k = 0; k < 2; ++k)
            s[k] += __shfl_xor(s[k], mask, 64);
    }
    if (lane == 0) {
        pooled[0][wave * 2 + 0] = s[0];
        pooled[0][wave * 2 + 1] = s[1];
    } else if (lane == 4) {
        pooled[1][wave * 2 + 0] = s[0];
        pooled[1][wave * 2 + 1] = s[1];
    }
    __syncthreads();

    // 384 threads -> 2 patches x 192 float4 outputs
    const int patch = t / E4;            // 0 = left (j=2jj), 1 = right
    const int e4    = t - patch * E4;

    float4 acc = make_float4(0.f, 0.f, 0.f, 0.f);
    const float4* __restrict__ w4 = reinterpret_cast<const float4*>(w);
#pragma unroll
    for (int c = 0; c < CH; ++c) {
        const float  pc = pooled[patch][c];
        const float4 wv = w4[c * E4 + e4];
        acc.x += pc * wv.x;
        acc.y += pc * wv.y;
        acc.z += pc * wv.z;
        acc.w += pc * wv.w;
    }
    const int j = jj * 2 + patch;
    reinterpret_cast<float4*>(out)[((size_t)(b * NPP) + i * NP + j) * E4 + e4] = acc;
}

extern "C" void kernel_launch(void* const* d_in, const int* in_sizes, int n_in,
                              void* d_out, int out_size, void* d_ws, size_t ws_size,
                              hipStream_t stream) {
    const float* x = (const float*)d_in[0];
    const float* w = (const float*)d_in[1];
    float* out = (float*)d_out;

    dcsp_fused_kernel<<<BATCH * NP * (NP / 2), 384, 0, stream>>>(x, w, out);
}